// Round 1
// baseline (256.341 us; speedup 1.0000x reference)
//
#include <hip/hip_runtime.h>
#include <math.h>

#define NN 1024
#define NPIX (NN * NN)
#define NB 16
#define BPB 128                 // blocks per batch in K1/K3
#define NBLK (NB * BPB)         // 2048
#define CHUNK (NPIX / BPB)      // 8192 pixels per block
#define RADIUS 4.76837158203125e-07f  // 1/N^2/2 = 2^-21, exact in fp32

struct Partial {
    float m1, d1; int i1;       // variant 1: masked = hist * sal
    float m2, d2; int i2;       // variant 2: masked = sal (hist forced to ones)
    unsigned flags;             // bit0: any hist!=0 ; bit1: any m1!=0 ; bit2: any m2!=0
    int pad;
};

__device__ __forceinline__ void comp_upd(float om, float od, int oi,
                                         float& bm, float& bd, int& bi) {
    // lexicographic max on (m desc, d asc, idx asc)
    if (om > bm || (om == bm && (od < bd || (od == bd && oi < bi)))) {
        bm = om; bd = od; bi = oi;
    }
}

// ---------------- Kernel 1: streaming composite reduction ----------------
__global__ __launch_bounds__(256) void k_reduce(
        const float* __restrict__ sal, const float* __restrict__ hist,
        const float* __restrict__ cur, const float* __restrict__ grid,
        Partial* __restrict__ part) {
    __shared__ float r[NN];
    __shared__ Partial sp[4];
    for (int i = threadIdx.x; i < NN; i += 256) r[i] = grid[i * 2];  // row 0, ch x == linspace
    const int b   = blockIdx.x / BPB;
    const int blk = blockIdx.x % BPB;
    const float cx = cur[b * 2 + 0];
    const float cy = cur[b * 2 + 1];
    __syncthreads();

    const int base = b * NPIX + blk * CHUNK;
    float bm1 = -INFINITY, bd1 = INFINITY; int bi1 = 0x7fffffff;
    float bm2 = -INFINITY, bd2 = INFINITY; int bi2 = 0x7fffffff;
    unsigned fl = 0;

    for (int off = threadIdx.x * 4; off < CHUNK; off += 256 * 4) {
        const float4 s4 = *(const float4*)(sal + base + off);
        const float4 h4 = *(const float4*)(hist + base + off);
        const int p0 = blk * CHUNK + off;   // pixel index within batch
        #pragma unroll
        for (int j = 0; j < 4; ++j) {
            const int p = p0 + j;
            const float sv = ((const float*)&s4)[j];
            const float hv = ((const float*)&h4)[j];
            const int x = p & (NN - 1);
            const int y = p >> 10;
            const float dx = r[x] - cx;
            const float dy = r[y] - cy;
            const float cd = (dx * dx + dy * dy) * 0.5f;  // == cur_dist == d
            const float salv = (cd <= RADIUS) ? 0.0f : sv;
            const float m1 = hv * salv;
            const float m2 = salv;
            fl |= (hv != 0.0f) ? 1u : 0u;
            fl |= (m1 != 0.0f) ? 2u : 0u;
            fl |= (m2 != 0.0f) ? 4u : 0u;
            // ascending p within thread -> strict compares keep first index
            if (m1 > bm1 || (m1 == bm1 && cd < bd1)) { bm1 = m1; bd1 = cd; bi1 = p; }
            if (m2 > bm2 || (m2 == bm2 && cd < bd2)) { bm2 = m2; bd2 = cd; bi2 = p; }
        }
    }

    // wave butterfly reduce (64 lanes)
    #pragma unroll
    for (int s = 32; s; s >>= 1) {
        float om = __shfl_xor(bm1, s); float od = __shfl_xor(bd1, s); int oi = __shfl_xor(bi1, s);
        comp_upd(om, od, oi, bm1, bd1, bi1);
        om = __shfl_xor(bm2, s); od = __shfl_xor(bd2, s); oi = __shfl_xor(bi2, s);
        comp_upd(om, od, oi, bm2, bd2, bi2);
        fl |= __shfl_xor(fl, s);
    }
    const int wave = threadIdx.x >> 6;
    const int lane = threadIdx.x & 63;
    if (lane == 0) {
        Partial P; P.m1 = bm1; P.d1 = bd1; P.i1 = bi1;
        P.m2 = bm2; P.d2 = bd2; P.i2 = bi2; P.flags = fl; P.pad = 0;
        sp[wave] = P;
    }
    __syncthreads();
    if (threadIdx.x == 0) {
        Partial P = sp[0];
        for (int w = 1; w < 4; ++w) {
            const Partial Q = sp[w];
            comp_upd(Q.m1, Q.d1, Q.i1, P.m1, P.d1, P.i1);
            comp_upd(Q.m2, Q.d2, Q.i2, P.m2, P.d2, P.i2);
            P.flags |= Q.flags;
        }
        part[blockIdx.x] = P;
    }
}

// ---------------- Kernel 2: finalize (1 block, 16 waves = 1 per batch) ----------------
__global__ __launch_bounds__(1024) void k_final(
        const Partial* __restrict__ part, const float* __restrict__ sal,
        const float* __restrict__ cur, const float* __restrict__ grid,
        float* __restrict__ out_xy, float* __restrict__ params) {
    __shared__ unsigned shf[16];
    unsigned f = 0;
    for (int i = threadIdx.x; i < NBLK; i += 1024) f |= part[i].flags;
    #pragma unroll
    for (int s = 32; s; s >>= 1) f |= __shfl_xor(f, s);
    const int wave = threadIdx.x >> 6;
    const int lane = threadIdx.x & 63;
    if (lane == 0) shf[wave] = f;
    __syncthreads();
    unsigned allf = 0;
    #pragma unroll
    for (int w = 0; w < 16; ++w) allf |= shf[w];
    const bool histnz = (allf & 1u) != 0;   // !all(hist == 0)

    const int b = wave;
    float bm = -INFINITY, bd = INFINITY; int bi = 0x7fffffff;
    unsigned anz = 0;
    #pragma unroll
    for (int k = 0; k < 2; ++k) {
        const Partial Q = part[b * BPB + k * 64 + lane];
        const float m = histnz ? Q.m1 : Q.m2;
        const float d = histnz ? Q.d1 : Q.d2;
        const int   i = histnz ? Q.i1 : Q.i2;
        anz |= histnz ? (Q.flags & 2u) : (Q.flags & 4u);
        comp_upd(m, d, i, bm, bd, bi);
    }
    #pragma unroll
    for (int s = 32; s; s >>= 1) {
        const float om = __shfl_xor(bm, s);
        const float od = __shfl_xor(bd, s);
        const int   oi = __shfl_xor(bi, s);
        anz |= __shfl_xor(anz, s);
        comp_upd(om, od, oi, bm, bd, bi);
    }
    if (lane == 0) {
        const bool all_zero = (anz == 0u);            // all(masked == 0)
        const int idx = (bm > 0.0f) ? bi : 0;         // no valid pos -> argmin of all-inf = 0
        const int py = idx >> 10;
        const int px = idx & (NN - 1);
        const float lx = 2.0f * ((float)(px + 1) / 1024.0f) - 1.0f;
        const float ly = 2.0f * ((float)(py + 1) / 1024.0f) - 1.0f;
        // sm_value = sal (post cur-mask, pre-hist) at (py, px)
        const float gx = grid[px * 2];
        const float gy = grid[py * 2];
        const float cx = cur[b * 2 + 0];
        const float cy = cur[b * 2 + 1];
        const float dx = gx - cx;
        const float dy = gy - cy;
        const float cd = (dx * dx + dy * dy) * 0.5f;
        const float sv = sal[b * NPIX + idx];
        const float salv = (cd <= RADIUS) ? 0.0f : sv;
        const float sm = fmaxf(salv, 0.0001f);
        const float eps = 10.0f / sm;
        out_xy[2 * b + 0] = all_zero ? 1.0f : lx;
        out_xy[2 * b + 1] = all_zero ? 1.0f : ly;
        params[4 * b + 0] = lx;                        // rbf uses raw loc, not next_xy
        params[4 * b + 1] = ly;
        params[4 * b + 2] = eps;
        params[4 * b + 3] = histnz ? 0.0f : 1.0f;      // 1 -> treat hist as ones
    }
}

// ---------------- Kernel 3: RBF mask + hist update ----------------
__global__ __launch_bounds__(256) void k_apply(
        const float* __restrict__ hist, const float* __restrict__ grid,
        const float* __restrict__ params, float* __restrict__ out_hist,
        float* __restrict__ out_mask) {
    __shared__ float r[NN];
    for (int i = threadIdx.x; i < NN; i += 256) r[i] = grid[i * 2];
    const int b   = blockIdx.x / BPB;
    const int blk = blockIdx.x % BPB;
    const float lx  = params[4 * b + 0];
    const float ly  = params[4 * b + 1];
    const float eps = params[4 * b + 2];
    const bool useones = params[4 * b + 3] != 0.0f;
    __syncthreads();

    const int base = b * NPIX + blk * CHUNK;
    for (int off = threadIdx.x * 4; off < CHUNK; off += 256 * 4) {
        const float4 h4 = *(const float4*)(hist + base + off);
        float4 m4, o4;
        const int p0 = blk * CHUNK + off;
        #pragma unroll
        for (int j = 0; j < 4; ++j) {
            const int p = p0 + j;
            const int x = p & (NN - 1);
            const int y = p >> 10;
            const float dx = r[x] - lx;
            const float dy = r[y] - ly;
            const float rbf = (dx * dx + dy * dy) * 0.5f;
            const float t = rbf * eps;
            const float mk = expf(-(t * t));
            const float hv = useones ? 1.0f : ((const float*)&h4)[j];
            float ho = hv * (1.0f - mk);
            ho = fminf(fmaxf(ho, 0.0f), 1.0f);
            ((float*)&m4)[j] = mk;
            ((float*)&o4)[j] = ho;
        }
        *(float4*)(out_mask + base + off) = m4;
        *(float4*)(out_hist + base + off) = o4;
    }
}

extern "C" void kernel_launch(void* const* d_in, const int* in_sizes, int n_in,
                              void* d_out, int out_size, void* d_ws, size_t ws_size,
                              hipStream_t stream) {
    const float* sal  = (const float*)d_in[0];   // (B, N, N)
    const float* hist = (const float*)d_in[1];   // (B, 1, N, N)
    const float* cur  = (const float*)d_in[2];   // (B, 2)
    const float* grid = (const float*)d_in[3];   // (N, N, 2)

    float* out      = (float*)d_out;
    float* out_xy   = out;                       // B*2
    float* out_hist = out + NB * 2;              // B*N*N
    float* out_mask = out_hist + NB * NPIX;      // B*N*N

    Partial* part = (Partial*)d_ws;              // NBLK * 32 B = 64 KiB
    float* params = (float*)((char*)d_ws + NBLK * sizeof(Partial));  // 16*4 floats

    k_reduce<<<NBLK, 256, 0, stream>>>(sal, hist, cur, grid, part);
    k_final<<<1, 1024, 0, stream>>>(part, sal, cur, grid, out_xy, params);
    k_apply<<<NBLK, 256, 0, stream>>>(hist, grid, params, out_hist, out_mask);
}